// Round 2
// baseline (561.500 us; speedup 1.0000x reference)
//
#include <hip/hip_runtime.h>
#include <stdint.h>

// Problem constants
constexpr int NBATCH = 4;
constexpr int CH     = 256;   // channels
constexpr int LEN    = 4096;  // sequence length
constexpr int LPOOL  = 1024;  // pooled length (LEN/4)
constexpr int NH     = 4;     // heads
constexpr int HD     = 64;    // head dim

// ---------------------------------------------------------------------------
// Compose BN2(BN1(x)) into one per-channel affine.
// BN(x) = x*inv + (beta - mean*inv), inv = gamma*rsqrt(var+eps)
__global__ __launch_bounds__(256) void prep_bn(
    const float* __restrict__ g1, const float* __restrict__ b1,
    const float* __restrict__ m1, const float* __restrict__ v1,
    const float* __restrict__ g2, const float* __restrict__ b2,
    const float* __restrict__ m2, const float* __restrict__ v2,
    float* __restrict__ scale, float* __restrict__ shift)
{
    int t = threadIdx.x;
    float inv1 = g1[t] * rsqrtf(v1[t] + 1e-5f);
    float inv2 = g2[t] * rsqrtf(v2[t] + 1e-5f);
    scale[t] = inv1 * inv2;
    shift[t] = (b1[t] - m1[t] * inv1) * inv2 + (b2[t] - m2[t] * inv2);
}

// ---------------------------------------------------------------------------
// avg+max pool over groups of 4 along L. out[i] where i = nc*LPOOL + l2.
__global__ __launch_bounds__(256) void pool_kernel(
    const float* __restrict__ x, float* __restrict__ out)
{
    int i = blockIdx.x * blockDim.x + threadIdx.x;
    float4 r = ((const float4*)x)[i];
    out[i] = (r.x + r.y + r.z + r.w) * 0.25f
           + fmaxf(fmaxf(r.x, r.y), fmaxf(r.z, r.w));
}

// ---------------------------------------------------------------------------
// Y[n][co][x] = sum_ci W[co][ci] * In[n][ci][x]  (+bias) (*scale+shift)
// W: f32 [256,256]; In: f32 [N,256,X].
// Output f32, optionally transposed to [n][x][co].
// Tile 64(co) x 64(x), 256 threads, 4x4 micro-tile, K staged by 16.
__global__ __launch_bounds__(256) void gemm256(
    const float* __restrict__ W,
    const float* __restrict__ In,
    const float* __restrict__ bias,   // nullable
    const float* __restrict__ scale,  // nullable (fused affine)
    const float* __restrict__ shift,
    float* __restrict__ outF,
    int X, int transOut)
{
    __shared__ float Ws[16][65]; // [j][row]
    __shared__ float Is[16][65]; // [j][col]

    int n = blockIdx.z;
    int colBase = blockIdx.x * 64;
    int rowBase = blockIdx.y * 64;
    int t  = threadIdx.x;
    int tx = t & 15;
    int ty = t >> 4;

    const float* inN = In + (size_t)n * CH * X;
    float acc[4][4] = {};

    for (int kk = 0; kk < CH; kk += 16) {
        #pragma unroll
        for (int i = 0; i < 4; i++) {
            int idx = t + i * 256;           // 0..1023
            int row = idx >> 4, j = idx & 15;
            Ws[j][row] = W[(rowBase + row) * CH + kk + j];
        }
        #pragma unroll
        for (int i = 0; i < 4; i++) {
            int idx = t + i * 256;
            int j = idx >> 6, col = idx & 63;
            Is[j][col] = inN[(size_t)(kk + j) * X + colBase + col];
        }
        __syncthreads();
        #pragma unroll
        for (int j = 0; j < 16; j++) {
            float a0 = Ws[j][ty * 4 + 0], a1 = Ws[j][ty * 4 + 1];
            float a2 = Ws[j][ty * 4 + 2], a3 = Ws[j][ty * 4 + 3];
            float b0 = Is[j][tx * 4 + 0], b1 = Is[j][tx * 4 + 1];
            float b2 = Is[j][tx * 4 + 2], b3 = Is[j][tx * 4 + 3];
            acc[0][0] += a0 * b0; acc[0][1] += a0 * b1; acc[0][2] += a0 * b2; acc[0][3] += a0 * b3;
            acc[1][0] += a1 * b0; acc[1][1] += a1 * b1; acc[1][2] += a1 * b2; acc[1][3] += a1 * b3;
            acc[2][0] += a2 * b0; acc[2][1] += a2 * b1; acc[2][2] += a2 * b2; acc[2][3] += a2 * b3;
            acc[3][0] += a3 * b0; acc[3][1] += a3 * b1; acc[3][2] += a3 * b2; acc[3][3] += a3 * b3;
        }
        __syncthreads();
    }

    #pragma unroll
    for (int r = 0; r < 4; r++) {
        int row = rowBase + ty * 4 + r;
        float badd = bias ? bias[row] : 0.0f;
        float sc = scale ? scale[row] : 1.0f;
        float sh = shift ? shift[row] : 0.0f;
        #pragma unroll
        for (int cc = 0; cc < 4; cc++) {
            int col = colBase + tx * 4 + cc;
            float y = (acc[r][cc] + badd) * sc + sh;
            if (!transOut) outF[((size_t)n * CH + row) * X + col] = y;
            else           outF[((size_t)n * X + col) * CH + row] = y;
        }
    }
}

// ---------------------------------------------------------------------------
// Fused attention. Block = (n, h, 8 q-rows). All 1024 scores in LDS
// (stored [l2][8] so the PV phase reads them as b128 broadcasts).
// qT: [N, LEN, CH] f32 ; K: [N, CH, LPOOL] f32 ; vT: [N, LPOOL, CH] f32
// O:  [N, CH, LEN] f32
__global__ __launch_bounds__(256) void attn_kernel(
    const float* __restrict__ qT, const float* __restrict__ K,
    const float* __restrict__ vT, float* __restrict__ O)
{
    __shared__ float S[LPOOL][8];       // 32 KB, scores [l2][row]
    __shared__ float qs[8][HD];         // 2 KB
    __shared__ float redbuf[4][8][HD];  // 8 KB
    __shared__ float rowsum[8];

    int lb = blockIdx.x;   // q-row block (8 rows)
    int h  = blockIdx.y;
    int n  = blockIdx.z;
    int t  = threadIdx.x;
    int l0 = lb * 8;

    // load 8 q rows (scaled by 1/sqrt(64)=0.125), coalesced over e
    {
        int e = t & 63, r2 = t >> 6;   // r2 in 0..3
        #pragma unroll
        for (int rr = 0; rr < 8; rr += 4) {
            int r = r2 + rr;
            qs[r][e] = qT[((size_t)n * LEN + l0 + r) * CH + h * HD + e] * 0.125f;
        }
    }
    __syncthreads();

    // scores: thread c handles l2 in {c, c+256, c+512, c+768} for all 8 rows
    {
        int c = t;
        const float* Kh = K + ((size_t)n * CH + h * HD) * LPOOL;
        float acc[4][8] = {};
        for (int e = 0; e < HD; e++) {
            float kv0 = Kh[(size_t)e * LPOOL + c];
            float kv1 = Kh[(size_t)e * LPOOL + c + 256];
            float kv2 = Kh[(size_t)e * LPOOL + c + 512];
            float kv3 = Kh[(size_t)e * LPOOL + c + 768];
            #pragma unroll
            for (int r = 0; r < 8; r++) {
                float qv = qs[r][e];
                acc[0][r] += kv0 * qv;
                acc[1][r] += kv1 * qv;
                acc[2][r] += kv2 * qv;
                acc[3][r] += kv3 * qv;
            }
        }
        #pragma unroll
        for (int j = 0; j < 4; j++) {
            float4* p = (float4*)&S[c + j * 256][0];
            p[0] = make_float4(acc[j][0], acc[j][1], acc[j][2], acc[j][3]);
            p[1] = make_float4(acc[j][4], acc[j][5], acc[j][6], acc[j][7]);
        }
    }
    __syncthreads();

    // softmax: wave w handles rows 2w, 2w+1; 16 elems per lane per row
    {
        int wave = t >> 6, lane = t & 63;
        #pragma unroll
        for (int rr = 0; rr < 2; rr++) {
            int r = wave * 2 + rr;
            float vals[16];
            float m = -1e30f;
            #pragma unroll
            for (int j = 0; j < 16; j++) {
                vals[j] = S[lane + j * 64][r];
                m = fmaxf(m, vals[j]);
            }
            #pragma unroll
            for (int off = 32; off > 0; off >>= 1) m = fmaxf(m, __shfl_xor(m, off));
            float s = 0.0f;
            #pragma unroll
            for (int j = 0; j < 16; j++) {
                float p = __expf(vals[j] - m);
                s += p;
                S[lane + j * 64][r] = p;
            }
            #pragma unroll
            for (int off = 32; off > 0; off >>= 1) s += __shfl_xor(s, off);
            if (lane == 0) rowsum[r] = s;
        }
    }
    __syncthreads();

    // PV: wave g covers l2 in [g*256, g*256+256); lane = e. vT loads coalesced.
    {
        int g = t >> 6, e = t & 63;
        const float* vh = vT + (size_t)n * LPOOL * CH + h * HD;
        float acc[8] = {};
        for (int l2 = g * 256; l2 < g * 256 + 256; l2++) {
            float vv = vh[(size_t)l2 * CH + e];
            const float4* p = (const float4*)&S[l2][0];
            float4 p0 = p[0], p1 = p[1];
            acc[0] += p0.x * vv; acc[1] += p0.y * vv;
            acc[2] += p0.z * vv; acc[3] += p0.w * vv;
            acc[4] += p1.x * vv; acc[5] += p1.y * vv;
            acc[6] += p1.z * vv; acc[7] += p1.w * vv;
        }
        #pragma unroll
        for (int r = 0; r < 8; r++) redbuf[g][r][e] = acc[r];
    }
    __syncthreads();

    // reduce over the 4 waves, divide by rowsum, write O[n][h*64+e][l0+r]
    {
        int e = t & 63, r2 = t >> 6;
        #pragma unroll
        for (int rr = 0; rr < 8; rr += 4) {
            int r = r2 + rr;
            float s = redbuf[0][r][e] + redbuf[1][r][e] + redbuf[2][r][e] + redbuf[3][r][e];
            s /= rowsum[r];
            O[((size_t)n * CH + h * HD + e) * LEN + l0 + r] = s;
        }
    }
}

// ---------------------------------------------------------------------------
extern "C" void kernel_launch(void* const* d_in, const int* in_sizes, int n_in,
                              void* d_out, int out_size, void* d_ws, size_t ws_size,
                              hipStream_t stream)
{
    const float* x  = (const float*)d_in[0];
    const float* Wq = (const float*)d_in[1];
    const float* bq = (const float*)d_in[2];
    const float* Wk = (const float*)d_in[3];
    const float* bk = (const float*)d_in[4];
    const float* Wv = (const float*)d_in[5];
    const float* bv = (const float*)d_in[6];
    const float* Wo = (const float*)d_in[7];
    const float* bo = (const float*)d_in[8];
    const float* Wa = (const float*)d_in[9];
    const float* g1 = (const float*)d_in[10];
    const float* b1 = (const float*)d_in[11];
    const float* m1 = (const float*)d_in[12];
    const float* v1 = (const float*)d_in[13];
    const float* g2 = (const float*)d_in[14];
    const float* b2 = (const float*)d_in[15];
    const float* m2 = (const float*)d_in[16];
    const float* v2 = (const float*)d_in[17];

    float* wsf      = (float*)d_ws;
    float* bn_scale = wsf;            // 256
    float* bn_shift = wsf + 256;      // 256
    float* xa_pool  = wsf + 1024;                             // [N,CH,LPOOL]
    float* xa       = xa_pool + (size_t)NBATCH * CH * LPOOL;
    float* kbuf     = xa      + (size_t)NBATCH * CH * LPOOL;  // [N,CH,LPOOL]
    float* vT       = kbuf    + (size_t)NBATCH * CH * LPOOL;  // [N,LPOOL,CH]
    float* qT       = vT      + (size_t)NBATCH * CH * LPOOL;  // [N,LEN,CH]
    float* obuf     = qT      + (size_t)NBATCH * CH * LEN;    // [N,CH,LEN]

    // 1. BN affine compose
    prep_bn<<<1, 256, 0, stream>>>(g1, b1, m1, v1, g2, b2, m2, v2, bn_scale, bn_shift);

    // 2. q projection -> qT [N,LEN,CH]
    gemm256<<<dim3(LEN / 64, CH / 64, NBATCH), 256, 0, stream>>>(
        Wq, x, bq, nullptr, nullptr, qT, LEN, 1);

    // 3. pool
    pool_kernel<<<(NBATCH * CH * LPOOL) / 256, 256, 0, stream>>>(x, xa_pool);

    // 4. xa = BN2(BN1(Wa @ xa_pool))
    gemm256<<<dim3(LPOOL / 64, CH / 64, NBATCH), 256, 0, stream>>>(
        Wa, xa_pool, nullptr, bn_scale, bn_shift, xa, LPOOL, 0);

    // 5. k = Wk @ xa + bk  -> [N,CH,LPOOL]
    gemm256<<<dim3(LPOOL / 64, CH / 64, NBATCH), 256, 0, stream>>>(
        Wk, xa, bk, nullptr, nullptr, kbuf, LPOOL, 0);

    // 6. v = Wv @ xa + bv  -> vT [N,LPOOL,CH]
    gemm256<<<dim3(LPOOL / 64, CH / 64, NBATCH), 256, 0, stream>>>(
        Wv, xa, bv, nullptr, nullptr, vT, LPOOL, 1);

    // 7. attention -> obuf [N,CH,LEN]
    attn_kernel<<<dim3(LEN / 8, NH, NBATCH), 256, 0, stream>>>(qT, kbuf, vT, obuf);

    // 8. out = Wo @ obuf + bo -> f32 d_out [N,CH,LEN]
    gemm256<<<dim3(LEN / 64, CH / 64, NBATCH), 256, 0, stream>>>(
        Wo, obuf, bo, nullptr, nullptr, (float*)d_out, LEN, 0);
}

// Round 3
// 324.124 us; speedup vs baseline: 1.7324x; 1.7324x over previous
//
#include <hip/hip_runtime.h>
#include <stdint.h>

// Problem constants
constexpr int NBATCH = 4;
constexpr int CH     = 256;   // channels
constexpr int LEN    = 4096;  // sequence length
constexpr int LPOOL  = 1024;  // pooled length (LEN/4)
constexpr int NH     = 4;     // heads
constexpr int HD     = 64;    // head dim

typedef __attribute__((ext_vector_type(8))) short short8;   // 8 bf16 in 4 VGPRs
typedef __attribute__((ext_vector_type(4))) float float4e;  // MFMA C/D

__device__ __forceinline__ unsigned short f2bf(float f) {
    union { unsigned int i; float f; } v; v.f = f;
    unsigned int lsb = (v.i >> 16) & 1u;
    v.i += 0x7fffu + lsb;
    return (unsigned short)(v.i >> 16);
}

// ---------------------------------------------------------------------------
// Compose BN2(BN1(x)) into one per-channel affine.
__global__ __launch_bounds__(256) void prep_bn(
    const float* __restrict__ g1, const float* __restrict__ b1,
    const float* __restrict__ m1, const float* __restrict__ v1,
    const float* __restrict__ g2, const float* __restrict__ b2,
    const float* __restrict__ m2, const float* __restrict__ v2,
    float* __restrict__ scale, float* __restrict__ shift)
{
    int t = threadIdx.x;
    float inv1 = g1[t] * rsqrtf(v1[t] + 1e-5f);
    float inv2 = g2[t] * rsqrtf(v2[t] + 1e-5f);
    scale[t] = inv1 * inv2;
    shift[t] = (b1[t] - m1[t] * inv1) * inv2 + (b2[t] - m2[t] * inv2);
}

// ---------------------------------------------------------------------------
// avg+max pool over groups of 4 along L.
__global__ __launch_bounds__(256) void pool_kernel(
    const float* __restrict__ x, float* __restrict__ out)
{
    int i = blockIdx.x * blockDim.x + threadIdx.x;
    float4 r = ((const float4*)x)[i];
    out[i] = (r.x + r.y + r.z + r.w) * 0.25f
           + fmaxf(fmaxf(r.x, r.y), fmaxf(r.z, r.w));
}

// ---------------------------------------------------------------------------
// Y[n][co][x] = sum_ci W[co][ci] * In[n][ci][x]  (+bias) (*scale+shift) (*outScale)
// fp32 compute. Output fp32 (outF) or bf16 (outB); trans -> [n][x][co].
__global__ __launch_bounds__(256) void gemm256(
    const float* __restrict__ W,
    const float* __restrict__ In,
    const float* __restrict__ bias,   // nullable
    const float* __restrict__ scale,  // nullable (fused affine)
    const float* __restrict__ shift,
    float* __restrict__ outF,                 // nullable
    unsigned short* __restrict__ outB,        // nullable
    int X, int transOut, float outScale)
{
    __shared__ float Ws[16][65]; // [j][row]
    __shared__ float Is[16][65]; // [j][col]

    int n = blockIdx.z;
    int colBase = blockIdx.x * 64;
    int rowBase = blockIdx.y * 64;
    int t  = threadIdx.x;
    int tx = t & 15;
    int ty = t >> 4;

    const float* inN = In + (size_t)n * CH * X;
    float acc[4][4] = {};

    for (int kk = 0; kk < CH; kk += 16) {
        #pragma unroll
        for (int i = 0; i < 4; i++) {
            int idx = t + i * 256;
            int row = idx >> 4, j = idx & 15;
            Ws[j][row] = W[(rowBase + row) * CH + kk + j];
        }
        #pragma unroll
        for (int i = 0; i < 4; i++) {
            int idx = t + i * 256;
            int j = idx >> 6, col = idx & 63;
            Is[j][col] = inN[(size_t)(kk + j) * X + colBase + col];
        }
        __syncthreads();
        #pragma unroll
        for (int j = 0; j < 16; j++) {
            float a0 = Ws[j][ty * 4 + 0], a1 = Ws[j][ty * 4 + 1];
            float a2 = Ws[j][ty * 4 + 2], a3 = Ws[j][ty * 4 + 3];
            float b0 = Is[j][tx * 4 + 0], b1 = Is[j][tx * 4 + 1];
            float b2 = Is[j][tx * 4 + 2], b3 = Is[j][tx * 4 + 3];
            acc[0][0] += a0 * b0; acc[0][1] += a0 * b1; acc[0][2] += a0 * b2; acc[0][3] += a0 * b3;
            acc[1][0] += a1 * b0; acc[1][1] += a1 * b1; acc[1][2] += a1 * b2; acc[1][3] += a1 * b3;
            acc[2][0] += a2 * b0; acc[2][1] += a2 * b1; acc[2][2] += a2 * b2; acc[2][3] += a2 * b3;
            acc[3][0] += a3 * b0; acc[3][1] += a3 * b1; acc[3][2] += a3 * b2; acc[3][3] += a3 * b3;
        }
        __syncthreads();
    }

    #pragma unroll
    for (int r = 0; r < 4; r++) {
        int row = rowBase + ty * 4 + r;
        float badd = bias ? bias[row] : 0.0f;
        float sc = scale ? scale[row] : 1.0f;
        float sh = shift ? shift[row] : 0.0f;
        #pragma unroll
        for (int cc = 0; cc < 4; cc++) {
            int col = colBase + tx * 4 + cc;
            float y = ((acc[r][cc] + badd) * sc + sh) * outScale;
            if (outF) {
                if (!transOut) outF[((size_t)n * CH + row) * X + col] = y;
                else           outF[((size_t)n * X + col) * CH + row] = y;
            } else {
                if (!transOut) outB[((size_t)n * CH + row) * X + col] = f2bf(y);
                else           outB[((size_t)n * X + col) * CH + row] = f2bf(y);
            }
        }
    }
}

// ---------------------------------------------------------------------------
// MFMA flash attention.
// Qb: [N, L, C]  bf16, pre-scaled by 1/8
// Kb: [N, L2, C] bf16
// Vb: [N, C, L2] bf16
// O : [N, C, L]  f32
// Block: 64 q-rows (4 waves x 16), iterate 8 key-tiles of 128 keys.
// S^T = K·Q^T via mfma_16x16x32 (D col=q(lane&15), row=key(quad*4+reg));
// online softmax; P through LDS into B-frag layout; O^T = V^T·P^T.
__global__ __launch_bounds__(256) void attn_mfma(
    const unsigned short* __restrict__ Qb,
    const unsigned short* __restrict__ Kb,
    const unsigned short* __restrict__ Vb,
    float* __restrict__ O)
{
    __shared__ unsigned short Ks[128 * 72];    // K-tile [key][e], row stride 72 (pad 8)
    __shared__ unsigned short Vs[64 * 136];    // V^T-tile [e][key], row stride 136 (pad 8)
    __shared__ unsigned short Ps[4 * 16 * 136];// per-wave P [q][key], stride 136

    int qb = blockIdx.x;          // 64-row q block
    int h  = blockIdx.y;
    int n  = blockIdx.z;
    int t  = threadIdx.x;
    int wave = t >> 6, lane = t & 63;
    int m = lane & 15, quad = lane >> 4;
    int l0 = qb * 64 + wave * 16; // this wave's q-row base

    // Q B-fragments (held in registers for the whole kernel)
    const unsigned short* qp = Qb + ((size_t)n * LEN + l0 + m) * CH + h * HD + quad * 8;
    short8 bQ0 = *(const short8*)qp;
    short8 bQ1 = *(const short8*)(qp + 32);

    float4e Oa[4] = {};  // O^T accumulator: eb-th block, row e=eb*16+quad*4+reg, col q=m
    float m_run = -INFINITY, l_run = 0.0f;

    unsigned short* Pw = Ps + wave * 16 * 136;

    const unsigned short* KgBase = Kb + (size_t)n * LPOOL * CH + h * HD;
    const unsigned short* VgBase = Vb + ((size_t)n * CH + h * HD) * LPOOL;

    for (int kt = 0; kt < 8; kt++) {
        __syncthreads();   // protect K/V LDS from previous iteration's readers
        // stage K tile: 128 rows x 64 bf16
        {
            const unsigned short* Kg = KgBase + (size_t)kt * 128 * CH;
            #pragma unroll
            for (int i = 0; i < 4; i++) {
                int idx = t + i * 256;
                int row = idx >> 3, ch = idx & 7;
                *(uint4*)&Ks[row * 72 + ch * 8] =
                    *(const uint4*)(Kg + (size_t)row * CH + ch * 8);
            }
        }
        // stage V^T tile: 64 rows(e) x 128 bf16(keys)
        {
            const unsigned short* Vg = VgBase + kt * 128;
            #pragma unroll
            for (int i = 0; i < 4; i++) {
                int idx = t + i * 256;
                int e = idx >> 4, ch = idx & 15;
                *(uint4*)&Vs[e * 136 + ch * 8] =
                    *(const uint4*)(Vg + (size_t)e * LPOOL + ch * 8);
            }
        }
        __syncthreads();

        // scores S^T for 128 keys x 16 q  (8 sub-tiles of 16 keys)
        float4e S[8];
        #pragma unroll
        for (int kb = 0; kb < 8; kb++) {
            const unsigned short* kp = &Ks[(kb * 16 + m) * 72 + quad * 8];
            short8 a0 = *(const short8*)kp;
            short8 a1 = *(const short8*)(kp + 32);
            float4e c = {};
            c = __builtin_amdgcn_mfma_f32_16x16x32_bf16(a0, bQ0, c, 0, 0, 0);
            c = __builtin_amdgcn_mfma_f32_16x16x32_bf16(a1, bQ1, c, 0, 0, 0);
            S[kb] = c;
        }

        // online softmax (row = fixed q = m; spread over 4 quads)
        float tm = -INFINITY;
        #pragma unroll
        for (int kb = 0; kb < 8; kb++)
            #pragma unroll
            for (int r = 0; r < 4; r++) tm = fmaxf(tm, S[kb][r]);
        tm = fmaxf(tm, __shfl_xor(tm, 16));
        tm = fmaxf(tm, __shfl_xor(tm, 32));
        float m_new = fmaxf(m_run, tm);
        float alpha = __expf(m_run - m_new);   // first tile: exp(-inf)=0
        float ts = 0.0f;
        #pragma unroll
        for (int kb = 0; kb < 8; kb++) {
            float p0 = __expf(S[kb][0] - m_new);
            float p1 = __expf(S[kb][1] - m_new);
            float p2 = __expf(S[kb][2] - m_new);
            float p3 = __expf(S[kb][3] - m_new);
            ts += (p0 + p1) + (p2 + p3);
            uint2 pk;
            pk.x = (unsigned)f2bf(p0) | ((unsigned)f2bf(p1) << 16);
            pk.y = (unsigned)f2bf(p2) | ((unsigned)f2bf(p3) << 16);
            *(uint2*)&Pw[m * 136 + kb * 16 + quad * 4] = pk;
        }
        ts += __shfl_xor(ts, 16);
        ts += __shfl_xor(ts, 32);
        l_run = l_run * alpha + ts;
        m_run = m_new;

        // rescale O by alpha
        #pragma unroll
        for (int eb = 0; eb < 4; eb++)
            #pragma unroll
            for (int r = 0; r < 4; r++) Oa[eb][r] *= alpha;

        // PV: O^T += V^T · P^T  (4 chunks of 32 keys)
        #pragma unroll
        for (int ch2 = 0; ch2 < 4; ch2++) {
            short8 bP = *(const short8*)&Pw[m * 136 + ch2 * 32 + quad * 8];
            #pragma unroll
            for (int eb = 0; eb < 4; eb++) {
                short8 aV = *(const short8*)&Vs[(eb * 16 + m) * 136 + ch2 * 32 + quad * 8];
                Oa[eb] = __builtin_amdgcn_mfma_f32_16x16x32_bf16(aV, bP, Oa[eb], 0, 0, 0);
            }
        }
    }

    float inv = 1.0f / l_run;
    #pragma unroll
    for (int eb = 0; eb < 4; eb++) {
        #pragma unroll
        for (int r = 0; r < 4; r++) {
            int e = eb * 16 + quad * 4 + r;
            O[((size_t)n * CH + h * HD + e) * LEN + l0 + m] = Oa[eb][r] * inv;
        }
    }
}

// ---------------------------------------------------------------------------
extern "C" void kernel_launch(void* const* d_in, const int* in_sizes, int n_in,
                              void* d_out, int out_size, void* d_ws, size_t ws_size,
                              hipStream_t stream)
{
    const float* x  = (const float*)d_in[0];
    const float* Wq = (const float*)d_in[1];
    const float* bq = (const float*)d_in[2];
    const float* Wk = (const float*)d_in[3];
    const float* bk = (const float*)d_in[4];
    const float* Wv = (const float*)d_in[5];
    const float* bv = (const float*)d_in[6];
    const float* Wo = (const float*)d_in[7];
    const float* bo = (const float*)d_in[8];
    const float* Wa = (const float*)d_in[9];
    const float* g1 = (const float*)d_in[10];
    const float* b1 = (const float*)d_in[11];
    const float* m1 = (const float*)d_in[12];
    const float* v1 = (const float*)d_in[13];
    const float* g2 = (const float*)d_in[14];
    const float* b2 = (const float*)d_in[15];
    const float* m2 = (const float*)d_in[16];
    const float* v2 = (const float*)d_in[17];

    float* wsf      = (float*)d_ws;
    float* bn_scale = wsf;            // 256
    float* bn_shift = wsf + 256;      // 256
    float* xa_pool  = wsf + 1024;                              // [N,CH,LPOOL] f32
    float* xa       = xa_pool + (size_t)NBATCH * CH * LPOOL;   // [N,CH,LPOOL] f32
    float* obuf     = xa      + (size_t)NBATCH * CH * LPOOL;   // [N,CH,LEN]   f32
    unsigned short* Qbf = (unsigned short*)(obuf + (size_t)NBATCH * CH * LEN);   // [N,L,C] bf16
    unsigned short* Kbf = Qbf + (size_t)NBATCH * LEN * CH;                        // [N,L2,C] bf16
    unsigned short* Vbf = Kbf + (size_t)NBATCH * LPOOL * CH;                      // [N,C,L2] bf16

    // 1. BN affine compose
    prep_bn<<<1, 256, 0, stream>>>(g1, b1, m1, v1, g2, b2, m2, v2, bn_scale, bn_shift);

    // 2. q projection -> bf16 [N,L,C], pre-scaled by 1/8
    gemm256<<<dim3(LEN / 64, CH / 64, NBATCH), 256, 0, stream>>>(
        Wq, x, bq, nullptr, nullptr, nullptr, Qbf, LEN, 1, 0.125f);

    // 3. pool
    pool_kernel<<<(NBATCH * CH * LPOOL) / 256, 256, 0, stream>>>(x, xa_pool);

    // 4. xa = BN2(BN1(Wa @ xa_pool)) f32
    gemm256<<<dim3(LPOOL / 64, CH / 64, NBATCH), 256, 0, stream>>>(
        Wa, xa_pool, nullptr, bn_scale, bn_shift, xa, nullptr, LPOOL, 0, 1.0f);

    // 5. k = Wk @ xa + bk -> bf16 [N,L2,C]
    gemm256<<<dim3(LPOOL / 64, CH / 64, NBATCH), 256, 0, stream>>>(
        Wk, xa, bk, nullptr, nullptr, nullptr, Kbf, LPOOL, 1, 1.0f);

    // 6. v = Wv @ xa + bv -> bf16 [N,C,L2]
    gemm256<<<dim3(LPOOL / 64, CH / 64, NBATCH), 256, 0, stream>>>(
        Wv, xa, bv, nullptr, nullptr, nullptr, Vbf, LPOOL, 0, 1.0f);

    // 7. MFMA flash attention -> obuf f32 [N,CH,LEN]
    attn_mfma<<<dim3(LEN / 64, NH, NBATCH), 256, 0, stream>>>(Qbf, Kbf, Vbf, obuf);

    // 8. out = Wo @ obuf + bo -> f32 d_out
    gemm256<<<dim3(LEN / 64, CH / 64, NBATCH), 256, 0, stream>>>(
        Wo, obuf, bo, nullptr, nullptr, (float*)d_out, nullptr, LEN, 0, 1.0f);
}

// Round 4
// 262.274 us; speedup vs baseline: 2.1409x; 1.2358x over previous
//
#include <hip/hip_runtime.h>
#include <stdint.h>

// Problem constants
constexpr int NBATCH = 4;
constexpr int CH     = 256;   // channels
constexpr int LEN    = 4096;  // sequence length
constexpr int LPOOL  = 1024;  // pooled length (LEN/4)
constexpr int NH     = 4;     // heads
constexpr int HD     = 64;    // head dim

typedef __attribute__((ext_vector_type(8))) short short8;   // 8 bf16 in 4 VGPRs
typedef __attribute__((ext_vector_type(4))) float float4e;  // MFMA C/D

__device__ __forceinline__ unsigned short f2bf(float f) {
    union { unsigned int i; float f; } v; v.f = f;
    unsigned int lsb = (v.i >> 16) & 1u;
    v.i += 0x7fffu + lsb;
    return (unsigned short)(v.i >> 16);
}

// ---------------------------------------------------------------------------
__global__ __launch_bounds__(256) void prep_bn(
    const float* __restrict__ g1, const float* __restrict__ b1,
    const float* __restrict__ m1, const float* __restrict__ v1,
    const float* __restrict__ g2, const float* __restrict__ b2,
    const float* __restrict__ m2, const float* __restrict__ v2,
    float* __restrict__ scale, float* __restrict__ shift)
{
    int t = threadIdx.x;
    float inv1 = g1[t] * rsqrtf(v1[t] + 1e-5f);
    float inv2 = g2[t] * rsqrtf(v2[t] + 1e-5f);
    scale[t] = inv1 * inv2;
    shift[t] = (b1[t] - m1[t] * inv1) * inv2 + (b2[t] - m2[t] * inv2);
}

// ---------------------------------------------------------------------------
// Cast the 5 weight matrices (each 256x256 f32) to bf16, packed sequentially.
__global__ __launch_bounds__(256) void cast_weights(
    const float* __restrict__ w0, const float* __restrict__ w1,
    const float* __restrict__ w2, const float* __restrict__ w3,
    const float* __restrict__ w4, unsigned short* __restrict__ out)
{
    int gid = blockIdx.x * 256 + threadIdx.x;        // 5*16384 chunks of 4
    int w = gid >> 14;
    int off = (gid & 16383) * 4;
    const float* src = (w == 0) ? w0 : (w == 1) ? w1 : (w == 2) ? w2 : (w == 3) ? w3 : w4;
    float4 v = *(const float4*)(src + off);
    uint2 pk;
    pk.x = (unsigned)f2bf(v.x) | ((unsigned)f2bf(v.y) << 16);
    pk.y = (unsigned)f2bf(v.z) | ((unsigned)f2bf(v.w) << 16);
    *(uint2*)(out + w * 65536 + off) = pk;
}

// ---------------------------------------------------------------------------
// x [N,C,L] f32 -> xbf [N,L,C] bf16 (64x64 LDS tile transpose)
__global__ __launch_bounds__(256) void transpose_cast(
    const float* __restrict__ x, unsigned short* __restrict__ out)
{
    __shared__ float T[64][65];
    int n = blockIdx.z, c0 = blockIdx.y * 64, l0 = blockIdx.x * 64;
    const float* xp = x + ((size_t)n * CH + c0) * LEN + l0;
    int t = threadIdx.x;
    #pragma unroll
    for (int i = 0; i < 4; i++) {
        int idx = t + i * 256;
        int c = idx >> 4, l4 = idx & 15;
        float4 v = *(const float4*)(xp + (size_t)c * LEN + l4 * 4);
        T[c][l4 * 4 + 0] = v.x; T[c][l4 * 4 + 1] = v.y;
        T[c][l4 * 4 + 2] = v.z; T[c][l4 * 4 + 3] = v.w;
    }
    __syncthreads();
    unsigned short* op = out + ((size_t)n * LEN + l0) * CH + c0;
    #pragma unroll
    for (int i = 0; i < 4; i++) {
        int idx = t + i * 256;
        int l = idx >> 4, c4 = idx & 15;
        uint2 pk;
        pk.x = (unsigned)f2bf(T[c4 * 4 + 0][l]) | ((unsigned)f2bf(T[c4 * 4 + 1][l]) << 16);
        pk.y = (unsigned)f2bf(T[c4 * 4 + 2][l]) | ((unsigned)f2bf(T[c4 * 4 + 3][l]) << 16);
        *(uint2*)(op + (size_t)l * CH + c4 * 4) = pk;
    }
}

// ---------------------------------------------------------------------------
// pool x [N,C,L] f32 (mean+max over 4) -> [N,LPOOL,C] bf16 transposed
__global__ __launch_bounds__(256) void pool_transpose(
    const float* __restrict__ x, unsigned short* __restrict__ out)
{
    __shared__ float T[64][65];
    int n = blockIdx.z, c0 = blockIdx.y * 64, p0 = blockIdx.x * 64;
    const float* xp = x + ((size_t)n * CH + c0) * LEN + p0 * 4;
    int t = threadIdx.x;
    #pragma unroll
    for (int i = 0; i < 16; i++) {
        int idx = t + i * 256;
        int c = idx >> 6, p = idx & 63;
        float4 r = *(const float4*)(xp + (size_t)c * LEN + p * 4);
        T[c][p] = (r.x + r.y + r.z + r.w) * 0.25f
                + fmaxf(fmaxf(r.x, r.y), fmaxf(r.z, r.w));
    }
    __syncthreads();
    unsigned short* op = out + ((size_t)n * LPOOL + p0) * CH + c0;
    #pragma unroll
    for (int i = 0; i < 4; i++) {
        int idx = t + i * 256;
        int p = idx >> 4, c4 = idx & 15;
        uint2 pk;
        pk.x = (unsigned)f2bf(T[c4 * 4 + 0][p]) | ((unsigned)f2bf(T[c4 * 4 + 1][p]) << 16);
        pk.y = (unsigned)f2bf(T[c4 * 4 + 2][p]) | ((unsigned)f2bf(T[c4 * 4 + 3][p]) << 16);
        *(uint2*)(op + (size_t)p * CH + c4 * 4) = pk;
    }
}

// ---------------------------------------------------------------------------
// MFMA GEMM: D[i][j] = sum_k A[i][k] * B[j][k], K = 256 (bf16, K-contig rows).
// A: [M rows, 256], batched by aBatch (0 = shared). B: [NN rows, 256], bBatch.
// Epilogue: + biasRow[i] + biasCol[j]; *scale[i]+shift[i]; *outScale.
// outF: f32 [n][i][j] (ld = NN).  outB: bf16 at n*M*NN + j*colStride + i (pack 4 i).
// Tile 128(i) x 128(j), 4 waves (2x2 of 64x64), BK=64.
__global__ __launch_bounds__(256) void gemm_mfma(
    const unsigned short* __restrict__ A, size_t aBatch,
    const unsigned short* __restrict__ B, size_t bBatch,
    const float* __restrict__ biasRow, const float* __restrict__ biasCol,
    const float* __restrict__ scale, const float* __restrict__ shift,
    float* __restrict__ outF, unsigned short* __restrict__ outB,
    int NN, int M, int colStride, float outScale)
{
    __shared__ unsigned short As[128 * 72];
    __shared__ unsigned short Bs[128 * 72];

    int n = blockIdx.z;
    int t = threadIdx.x;
    int wave = t >> 6, lane = t & 63, m = lane & 15, quad = lane >> 4;
    int wm = wave & 1, wn = wave >> 1;

    const unsigned short* Ab = A + (size_t)n * aBatch + (size_t)(blockIdx.y * 128) * 256;
    const unsigned short* Bb = B + (size_t)n * bBatch + (size_t)(blockIdx.x * 128) * 256;

    float4e acc[4][4] = {};

    for (int kk = 0; kk < 256; kk += 64) {
        #pragma unroll
        for (int i = 0; i < 4; i++) {
            int idx = t + i * 256;
            int row = idx >> 3, ch = idx & 7;
            *(uint4*)&As[row * 72 + ch * 8] = *(const uint4*)(Ab + (size_t)row * 256 + kk + ch * 8);
            *(uint4*)&Bs[row * 72 + ch * 8] = *(const uint4*)(Bb + (size_t)row * 256 + kk + ch * 8);
        }
        __syncthreads();
        #pragma unroll
        for (int kc = 0; kc < 2; kc++) {
            short8 af[4], bfr[4];
            #pragma unroll
            for (int i = 0; i < 4; i++)
                af[i] = *(const short8*)&As[(wm * 64 + i * 16 + m) * 72 + kc * 32 + quad * 8];
            #pragma unroll
            for (int j = 0; j < 4; j++)
                bfr[j] = *(const short8*)&Bs[(wn * 64 + j * 16 + m) * 72 + kc * 32 + quad * 8];
            #pragma unroll
            for (int i = 0; i < 4; i++)
                #pragma unroll
                for (int j = 0; j < 4; j++)
                    acc[i][j] = __builtin_amdgcn_mfma_f32_16x16x32_bf16(af[i], bfr[j], acc[i][j], 0, 0, 0);
        }
        __syncthreads();
    }

    size_t outBase = (size_t)n * (size_t)M * (size_t)NN;
    #pragma unroll
    for (int i = 0; i < 4; i++) {
        int rowBase = blockIdx.y * 128 + wm * 64 + i * 16 + quad * 4;
        float br[4], sc[4], sh[4];
        #pragma unroll
        for (int r = 0; r < 4; r++) {
            br[r] = biasRow ? biasRow[rowBase + r] : 0.0f;
            sc[r] = scale ? scale[rowBase + r] : 1.0f;
            sh[r] = shift ? shift[rowBase + r] : 0.0f;
        }
        #pragma unroll
        for (int j = 0; j < 4; j++) {
            int col = blockIdx.x * 128 + wn * 64 + j * 16 + m;
            float bc = biasCol ? biasCol[col] : 0.0f;
            float4e c = acc[i][j];
            float vals[4];
            #pragma unroll
            for (int r = 0; r < 4; r++)
                vals[r] = ((c[r] + br[r] + bc) * sc[r] + sh[r]) * outScale;
            if (outF) {
                #pragma unroll
                for (int r = 0; r < 4; r++)
                    outF[outBase + (size_t)(rowBase + r) * NN + col] = vals[r];
            } else {
                uint2 pk;
                pk.x = (unsigned)f2bf(vals[0]) | ((unsigned)f2bf(vals[1]) << 16);
                pk.y = (unsigned)f2bf(vals[2]) | ((unsigned)f2bf(vals[3]) << 16);
                *(uint2*)&outB[outBase + (size_t)col * colStride + rowBase] = pk;
            }
        }
    }
}

// ---------------------------------------------------------------------------
// MFMA flash attention.
// Qb: [N, L, C] bf16 (pre-scaled 1/8); Kb: [N, L2, C] bf16; Vb: [N, C, L2] bf16
// Obf: [N, L, C] bf16 (O^T layout, feeds o-proj as B operand)
__global__ __launch_bounds__(256) void attn_mfma(
    const unsigned short* __restrict__ Qb,
    const unsigned short* __restrict__ Kb,
    const unsigned short* __restrict__ Vb,
    unsigned short* __restrict__ Obf)
{
    __shared__ unsigned short Ks[128 * 72];
    __shared__ unsigned short Vs[64 * 136];
    __shared__ unsigned short Ps[4 * 16 * 136];

    int qb = blockIdx.x;
    int h  = blockIdx.y;
    int n  = blockIdx.z;
    int t  = threadIdx.x;
    int wave = t >> 6, lane = t & 63;
    int m = lane & 15, quad = lane >> 4;
    int l0 = qb * 64 + wave * 16;

    const unsigned short* qp = Qb + ((size_t)n * LEN + l0 + m) * CH + h * HD + quad * 8;
    short8 bQ0 = *(const short8*)qp;
    short8 bQ1 = *(const short8*)(qp + 32);

    float4e Oa[4] = {};
    float m_run = -INFINITY, l_run = 0.0f;
    unsigned short* Pw = Ps + wave * 16 * 136;

    const unsigned short* KgBase = Kb + (size_t)n * LPOOL * CH + h * HD;
    const unsigned short* VgBase = Vb + ((size_t)n * CH + h * HD) * LPOOL;

    for (int kt = 0; kt < 8; kt++) {
        __syncthreads();
        {
            const unsigned short* Kg = KgBase + (size_t)kt * 128 * CH;
            #pragma unroll
            for (int i = 0; i < 4; i++) {
                int idx = t + i * 256;
                int row = idx >> 3, ch = idx & 7;
                *(uint4*)&Ks[row * 72 + ch * 8] = *(const uint4*)(Kg + (size_t)row * CH + ch * 8);
            }
        }
        {
            const unsigned short* Vg = VgBase + kt * 128;
            #pragma unroll
            for (int i = 0; i < 4; i++) {
                int idx = t + i * 256;
                int e = idx >> 4, ch = idx & 15;
                *(uint4*)&Vs[e * 136 + ch * 8] = *(const uint4*)(Vg + (size_t)e * LPOOL + ch * 8);
            }
        }
        __syncthreads();

        float4e S[8];
        #pragma unroll
        for (int kb = 0; kb < 8; kb++) {
            const unsigned short* kp = &Ks[(kb * 16 + m) * 72 + quad * 8];
            short8 a0 = *(const short8*)kp;
            short8 a1 = *(const short8*)(kp + 32);
            float4e c = {};
            c = __builtin_amdgcn_mfma_f32_16x16x32_bf16(a0, bQ0, c, 0, 0, 0);
            c = __builtin_amdgcn_mfma_f32_16x16x32_bf16(a1, bQ1, c, 0, 0, 0);
            S[kb] = c;
        }

        float tm = -INFINITY;
        #pragma unroll
        for (int kb = 0; kb < 8; kb++)
            #pragma unroll
            for (int r = 0; r < 4; r++) tm = fmaxf(tm, S[kb][r]);
        tm = fmaxf(tm, __shfl_xor(tm, 16));
        tm = fmaxf(tm, __shfl_xor(tm, 32));
        float m_new = fmaxf(m_run, tm);
        float alpha = __expf(m_run - m_new);
        float ts = 0.0f;
        #pragma unroll
        for (int kb = 0; kb < 8; kb++) {
            float p0 = __expf(S[kb][0] - m_new);
            float p1 = __expf(S[kb][1] - m_new);
            float p2 = __expf(S[kb][2] - m_new);
            float p3 = __expf(S[kb][3] - m_new);
            ts += (p0 + p1) + (p2 + p3);
            uint2 pk;
            pk.x = (unsigned)f2bf(p0) | ((unsigned)f2bf(p1) << 16);
            pk.y = (unsigned)f2bf(p2) | ((unsigned)f2bf(p3) << 16);
            *(uint2*)&Pw[m * 136 + kb * 16 + quad * 4] = pk;
        }
        ts += __shfl_xor(ts, 16);
        ts += __shfl_xor(ts, 32);
        l_run = l_run * alpha + ts;
        m_run = m_new;

        #pragma unroll
        for (int eb = 0; eb < 4; eb++)
            #pragma unroll
            for (int r = 0; r < 4; r++) Oa[eb][r] *= alpha;

        #pragma unroll
        for (int ch2 = 0; ch2 < 4; ch2++) {
            short8 bP = *(const short8*)&Pw[m * 136 + ch2 * 32 + quad * 8];
            #pragma unroll
            for (int eb = 0; eb < 4; eb++) {
                short8 aV = *(const short8*)&Vs[(eb * 16 + m) * 136 + ch2 * 32 + quad * 8];
                Oa[eb] = __builtin_amdgcn_mfma_f32_16x16x32_bf16(aV, bP, Oa[eb], 0, 0, 0);
            }
        }
    }

    // write O^T bf16 [N, L, C]: row l = l0+m, cols c = h*64 + eb*16 + quad*4 + r
    float inv = 1.0f / l_run;
    unsigned short* op = Obf + ((size_t)n * LEN + l0 + m) * CH + h * HD;
    #pragma unroll
    for (int eb = 0; eb < 4; eb++) {
        uint2 pk;
        pk.x = (unsigned)f2bf(Oa[eb][0] * inv) | ((unsigned)f2bf(Oa[eb][1] * inv) << 16);
        pk.y = (unsigned)f2bf(Oa[eb][2] * inv) | ((unsigned)f2bf(Oa[eb][3] * inv) << 16);
        *(uint2*)(op + eb * 16 + quad * 4) = pk;
    }
}

// ---------------------------------------------------------------------------
extern "C" void kernel_launch(void* const* d_in, const int* in_sizes, int n_in,
                              void* d_out, int out_size, void* d_ws, size_t ws_size,
                              hipStream_t stream)
{
    const float* x  = (const float*)d_in[0];
    const float* Wq = (const float*)d_in[1];
    const float* bq = (const float*)d_in[2];
    const float* Wk = (const float*)d_in[3];
    const float* bk = (const float*)d_in[4];
    const float* Wv = (const float*)d_in[5];
    const float* bv = (const float*)d_in[6];
    const float* Wo = (const float*)d_in[7];
    const float* bo = (const float*)d_in[8];
    const float* Wa = (const float*)d_in[9];
    const float* g1 = (const float*)d_in[10];
    const float* b1 = (const float*)d_in[11];
    const float* m1 = (const float*)d_in[12];
    const float* v1 = (const float*)d_in[13];
    const float* g2 = (const float*)d_in[14];
    const float* b2 = (const float*)d_in[15];
    const float* m2 = (const float*)d_in[16];
    const float* v2 = (const float*)d_in[17];

    float* wsf      = (float*)d_ws;
    float* bn_scale = wsf;
    float* bn_shift = wsf + 256;
    unsigned short* Wbf   = (unsigned short*)(wsf + 512);          // 5*65536
    unsigned short* xbf   = Wbf + 5 * 65536;                        // [N,L,C]
    unsigned short* poolT = xbf   + (size_t)NBATCH * LEN * CH;      // [N,L2,C]
    unsigned short* xabf  = poolT + (size_t)NBATCH * LPOOL * CH;    // [N,L2,C]
    unsigned short* Kbf   = xabf  + (size_t)NBATCH * LPOOL * CH;    // [N,L2,C]
    unsigned short* Vbf   = Kbf   + (size_t)NBATCH * LPOOL * CH;    // [N,C,L2]
    unsigned short* Qbf   = Vbf   + (size_t)NBATCH * LPOOL * CH;    // [N,L,C]
    unsigned short* Obf   = Qbf   + (size_t)NBATCH * LEN * CH;      // [N,L,C]

    prep_bn<<<1, 256, 0, stream>>>(g1, b1, m1, v1, g2, b2, m2, v2, bn_scale, bn_shift);
    cast_weights<<<320, 256, 0, stream>>>(Wq, Wk, Wv, Wo, Wa, Wbf);
    transpose_cast<<<dim3(64, 4, 4), 256, 0, stream>>>(x, xbf);
    pool_transpose<<<dim3(16, 4, 4), 256, 0, stream>>>(x, poolT);

    // q = Wq @ x + bq, pre-scaled 1/8 -> Qbf [N,L,C]
    gemm_mfma<<<dim3(32, 2, 4), 256, 0, stream>>>(
        Wbf + 0 * 65536, 0, xbf, (size_t)LEN * CH, bq, nullptr, nullptr, nullptr,
        nullptr, Qbf, LEN, 256, 256, 0.125f);

    // xa = BN2(BN1(Wa @ pool(x))) -> xabf [N,L2,C]
    gemm_mfma<<<dim3(8, 2, 4), 256, 0, stream>>>(
        Wbf + 4 * 65536, 0, poolT, (size_t)LPOOL * CH, nullptr, nullptr, bn_scale, bn_shift,
        nullptr, xabf, LPOOL, 256, 256, 1.0f);

    // k = Wk @ xa + bk -> Kbf [N,L2,C]
    gemm_mfma<<<dim3(8, 2, 4), 256, 0, stream>>>(
        Wbf + 1 * 65536, 0, xabf, (size_t)LPOOL * CH, bk, nullptr, nullptr, nullptr,
        nullptr, Kbf, LPOOL, 256, 256, 1.0f);

    // v = Wv @ xa + bv -> Vbf [N,C,L2]  (swapped operands: rows = l2, cols = co)
    gemm_mfma<<<dim3(2, 8, 4), 256, 0, stream>>>(
        xabf, (size_t)LPOOL * CH, Wbf + 2 * 65536, 0, nullptr, bv, nullptr, nullptr,
        nullptr, Vbf, 256, LPOOL, LPOOL, 1.0f);

    // attention -> Obf [N,L,C] bf16
    attn_mfma<<<dim3(LEN / 64, NH, NBATCH), 256, 0, stream>>>(Qbf, Kbf, Vbf, Obf);

    // out = Wo @ o + bo -> f32 d_out [N,C,L]
    gemm_mfma<<<dim3(32, 2, 4), 256, 0, stream>>>(
        Wbf + 3 * 65536, 0, Obf, (size_t)LEN * CH, bo, nullptr, nullptr, nullptr,
        (float*)d_out, nullptr, LEN, 256, 256, 1.0f);
}

// Round 5
// 192.241 us; speedup vs baseline: 2.9208x; 1.3643x over previous
//
#include <hip/hip_runtime.h>
#include <stdint.h>

// Problem constants
constexpr int NBATCH = 4;
constexpr int CH     = 256;   // channels
constexpr int LEN    = 4096;  // sequence length
constexpr int LPOOL  = 1024;  // pooled length (LEN/4)
constexpr int NH     = 4;     // heads
constexpr int HD     = 64;    // head dim

typedef __attribute__((ext_vector_type(8))) short short8;   // 8 bf16 in 4 VGPRs
typedef __attribute__((ext_vector_type(4))) float float4e;  // MFMA C/D

__device__ __forceinline__ unsigned short f2bf(float f) {
    union { unsigned int i; float f; } v; v.f = f;
    unsigned int lsb = (v.i >> 16) & 1u;
    v.i += 0x7fffu + lsb;
    return (unsigned short)(v.i >> 16);
}
// pack two floats -> two bf16 (round-half-up via +0x8000, then byte-perm)
__device__ __forceinline__ unsigned pack2bf(float lo, float hi) {
    unsigned a = __float_as_uint(lo) + 0x8000u;
    unsigned b = __float_as_uint(hi) + 0x8000u;
    return __builtin_amdgcn_perm(b, a, 0x07060302u);  // u16[0]=a.hi16, u16[1]=b.hi16
}

// ---------------------------------------------------------------------------
__global__ __launch_bounds__(256) void prep_bn(
    const float* __restrict__ g1, const float* __restrict__ b1,
    const float* __restrict__ m1, const float* __restrict__ v1,
    const float* __restrict__ g2, const float* __restrict__ b2,
    const float* __restrict__ m2, const float* __restrict__ v2,
    float* __restrict__ scale, float* __restrict__ shift)
{
    int t = threadIdx.x;
    float inv1 = g1[t] * rsqrtf(v1[t] + 1e-5f);
    float inv2 = g2[t] * rsqrtf(v2[t] + 1e-5f);
    scale[t] = inv1 * inv2;
    shift[t] = (b1[t] - m1[t] * inv1) * inv2 + (b2[t] - m2[t] * inv2);
}

// ---------------------------------------------------------------------------
__global__ __launch_bounds__(256) void cast_weights(
    const float* __restrict__ w0, const float* __restrict__ w1,
    const float* __restrict__ w2, const float* __restrict__ w3,
    const float* __restrict__ w4, unsigned short* __restrict__ out)
{
    int gid = blockIdx.x * 256 + threadIdx.x;
    int w = gid >> 14;
    int off = (gid & 16383) * 4;
    const float* src = (w == 0) ? w0 : (w == 1) ? w1 : (w == 2) ? w2 : (w == 3) ? w3 : w4;
    float4 v = *(const float4*)(src + off);
    uint2 pk;
    pk.x = (unsigned)f2bf(v.x) | ((unsigned)f2bf(v.y) << 16);
    pk.y = (unsigned)f2bf(v.z) | ((unsigned)f2bf(v.w) << 16);
    *(uint2*)(out + w * 65536 + off) = pk;
}

// ---------------------------------------------------------------------------
// x [N,C,L] f32 -> xbf [N,L,C] bf16 (64x64 LDS tile transpose)
__global__ __launch_bounds__(256) void transpose_cast(
    const float* __restrict__ x, unsigned short* __restrict__ out)
{
    __shared__ float T[64][65];
    int n = blockIdx.z, c0 = blockIdx.y * 64, l0 = blockIdx.x * 64;
    const float* xp = x + ((size_t)n * CH + c0) * LEN + l0;
    int t = threadIdx.x;
    #pragma unroll
    for (int i = 0; i < 4; i++) {
        int idx = t + i * 256;
        int c = idx >> 4, l4 = idx & 15;
        float4 v = *(const float4*)(xp + (size_t)c * LEN + l4 * 4);
        T[c][l4 * 4 + 0] = v.x; T[c][l4 * 4 + 1] = v.y;
        T[c][l4 * 4 + 2] = v.z; T[c][l4 * 4 + 3] = v.w;
    }
    __syncthreads();
    unsigned short* op = out + ((size_t)n * LEN + l0) * CH + c0;
    #pragma unroll
    for (int i = 0; i < 4; i++) {
        int idx = t + i * 256;
        int l = idx >> 4, c4 = idx & 15;
        uint2 pk;
        pk.x = (unsigned)f2bf(T[c4 * 4 + 0][l]) | ((unsigned)f2bf(T[c4 * 4 + 1][l]) << 16);
        pk.y = (unsigned)f2bf(T[c4 * 4 + 2][l]) | ((unsigned)f2bf(T[c4 * 4 + 3][l]) << 16);
        *(uint2*)(op + (size_t)l * CH + c4 * 4) = pk;
    }
}

// ---------------------------------------------------------------------------
// pool x [N,C,L] f32 (mean+max over 4) -> [N,LPOOL,C] bf16 transposed
__global__ __launch_bounds__(256) void pool_transpose(
    const float* __restrict__ x, unsigned short* __restrict__ out)
{
    __shared__ float T[64][65];
    int n = blockIdx.z, c0 = blockIdx.y * 64, p0 = blockIdx.x * 64;
    const float* xp = x + ((size_t)n * CH + c0) * LEN + p0 * 4;
    int t = threadIdx.x;
    #pragma unroll
    for (int i = 0; i < 16; i++) {
        int idx = t + i * 256;
        int c = idx >> 6, p = idx & 63;
        float4 r = *(const float4*)(xp + (size_t)c * LEN + p * 4);
        T[c][p] = (r.x + r.y + r.z + r.w) * 0.25f
                + fmaxf(fmaxf(r.x, r.y), fmaxf(r.z, r.w));
    }
    __syncthreads();
    unsigned short* op = out + ((size_t)n * LPOOL + p0) * CH + c0;
    #pragma unroll
    for (int i = 0; i < 4; i++) {
        int idx = t + i * 256;
        int p = idx >> 4, c4 = idx & 15;
        uint2 pk;
        pk.x = (unsigned)f2bf(T[c4 * 4 + 0][p]) | ((unsigned)f2bf(T[c4 * 4 + 1][p]) << 16);
        pk.y = (unsigned)f2bf(T[c4 * 4 + 2][p]) | ((unsigned)f2bf(T[c4 * 4 + 3][p]) << 16);
        *(uint2*)(op + (size_t)p * CH + c4 * 4) = pk;
    }
}

// ---------------------------------------------------------------------------
// MFMA GEMM: D[i][j] = sum_k A[i][k] * B[j][k], K = 256 (bf16, K-contig rows).
// Epilogue: + biasRow[i] + biasCol[j]; *scale[i]+shift[i]; *outScale.
// outF: f32 [n][i][j] (ld = NN). outB: bf16 at n*M*NN + j*colStride + i,
// restaged through LDS so global stores are 256B-contiguous rows.
__global__ __launch_bounds__(256) void gemm_mfma(
    const unsigned short* __restrict__ A, size_t aBatch,
    const unsigned short* __restrict__ B, size_t bBatch,
    const float* __restrict__ biasRow, const float* __restrict__ biasCol,
    const float* __restrict__ scale, const float* __restrict__ shift,
    float* __restrict__ outF, unsigned short* __restrict__ outB,
    int NN, int M, int colStride, float outScale)
{
    __shared__ unsigned short smem[2 * 128 * 72];  // As | Bs ; reused as TO[128][136]
    unsigned short* As = smem;
    unsigned short* Bs = smem + 128 * 72;

    int n = blockIdx.z;
    int t = threadIdx.x;
    int wave = t >> 6, lane = t & 63, m = lane & 15, quad = lane >> 4;
    int wm = wave & 1, wn = wave >> 1;

    const unsigned short* Ab = A + (size_t)n * aBatch + (size_t)(blockIdx.y * 128) * 256;
    const unsigned short* Bb = B + (size_t)n * bBatch + (size_t)(blockIdx.x * 128) * 256;

    float4e acc[4][4] = {};

    for (int kk = 0; kk < 256; kk += 64) {
        #pragma unroll
        for (int i = 0; i < 4; i++) {
            int idx = t + i * 256;
            int row = idx >> 3, ch = idx & 7;
            *(uint4*)&As[row * 72 + ch * 8] = *(const uint4*)(Ab + (size_t)row * 256 + kk + ch * 8);
            *(uint4*)&Bs[row * 72 + ch * 8] = *(const uint4*)(Bb + (size_t)row * 256 + kk + ch * 8);
        }
        __syncthreads();
        #pragma unroll
        for (int kc = 0; kc < 2; kc++) {
            short8 af[4], bfr[4];
            #pragma unroll
            for (int i = 0; i < 4; i++)
                af[i] = *(const short8*)&As[(wm * 64 + i * 16 + m) * 72 + kc * 32 + quad * 8];
            #pragma unroll
            for (int j = 0; j < 4; j++)
                bfr[j] = *(const short8*)&Bs[(wn * 64 + j * 16 + m) * 72 + kc * 32 + quad * 8];
            #pragma unroll
            for (int i = 0; i < 4; i++)
                #pragma unroll
                for (int j = 0; j < 4; j++)
                    acc[i][j] = __builtin_amdgcn_mfma_f32_16x16x32_bf16(af[i], bfr[j], acc[i][j], 0, 0, 0);
        }
        __syncthreads();
    }

    size_t outBase = (size_t)n * (size_t)M * (size_t)NN;
    if (outF) {
        #pragma unroll
        for (int i = 0; i < 4; i++) {
            int rowBase = blockIdx.y * 128 + wm * 64 + i * 16 + quad * 4;
            float br[4], sc[4], sh[4];
            #pragma unroll
            for (int r = 0; r < 4; r++) {
                br[r] = biasRow ? biasRow[rowBase + r] : 0.0f;
                sc[r] = scale ? scale[rowBase + r] : 1.0f;
                sh[r] = shift ? shift[rowBase + r] : 0.0f;
            }
            #pragma unroll
            for (int j = 0; j < 4; j++) {
                int col = blockIdx.x * 128 + wn * 64 + j * 16 + m;
                float bc = biasCol ? biasCol[col] : 0.0f;
                float4e c = acc[i][j];
                #pragma unroll
                for (int r = 0; r < 4; r++)
                    outF[outBase + (size_t)(rowBase + r) * NN + col] =
                        ((c[r] + br[r] + bc) * sc[r] + sh[r]) * outScale;
            }
        }
    } else {
        // restage tile (bf16) through LDS: TO[col_local][row_local], stride 136
        unsigned short* TO = smem;
        #pragma unroll
        for (int i = 0; i < 4; i++) {
            int rowL = wm * 64 + i * 16 + quad * 4;
            int rowBase = blockIdx.y * 128 + rowL;
            float br[4], sc[4], sh[4];
            #pragma unroll
            for (int r = 0; r < 4; r++) {
                br[r] = biasRow ? biasRow[rowBase + r] : 0.0f;
                sc[r] = scale ? scale[rowBase + r] : 1.0f;
                sh[r] = shift ? shift[rowBase + r] : 0.0f;
            }
            #pragma unroll
            for (int j = 0; j < 4; j++) {
                int colL = wn * 64 + j * 16 + m;
                float bc = biasCol ? biasCol[blockIdx.x * 128 + colL] : 0.0f;
                float4e c = acc[i][j];
                float v0 = ((c[0] + br[0] + bc) * sc[0] + sh[0]) * outScale;
                float v1 = ((c[1] + br[1] + bc) * sc[1] + sh[1]) * outScale;
                float v2 = ((c[2] + br[2] + bc) * sc[2] + sh[2]) * outScale;
                float v3 = ((c[3] + br[3] + bc) * sc[3] + sh[3]) * outScale;
                uint2 pk;
                pk.x = pack2bf(v0, v1);
                pk.y = pack2bf(v2, v3);
                *(uint2*)&TO[colL * 136 + rowL] = pk;
            }
        }
        __syncthreads();
        int col0 = blockIdx.x * 128, row0 = blockIdx.y * 128;
        #pragma unroll
        for (int w = 0; w < 8; w++) {
            int idx = t + w * 256;
            int l = idx >> 4, ch = idx & 15;
            *(uint4*)(outB + outBase + (size_t)(col0 + l) * colStride + row0 + ch * 8) =
                *(const uint4*)&TO[l * 136 + ch * 8];
        }
    }
}

// ---------------------------------------------------------------------------
// MFMA flash attention, fixed-shift softmax (no online max).
// Qb: [N, L, C] bf16, pre-scaled by log2(e)/8 ; Kb: [N, L2, C] bf16 ;
// Vb: [N, C, L2] bf16 ; Obf: [N, L, C] bf16 (O^T layout, feeds o-proj).
// Block = 128 q (4 waves x 32 q via 2 B-frags), 8 key-tiles of 128.
// p = exp2(S_mfma) where S acc is initialized to -12*log2e (shift cancels
// in normalization; scores are O(10) so no overflow/underflow risk).
__global__ __launch_bounds__(256) void attn_mfma(
    const unsigned short* __restrict__ Qb,
    const unsigned short* __restrict__ Kb,
    const unsigned short* __restrict__ Vb,
    unsigned short* __restrict__ Obf)
{
    __shared__ unsigned short Ks[128 * 72];      // K-tile [key][e]
    __shared__ unsigned short Vs[64 * 136];      // V^T-tile [e][key]
    __shared__ unsigned short Ps[4 * 32 * 136];  // per-wave P [q][key]

    int qb = blockIdx.x;          // 128-row q block
    int h  = blockIdx.y;
    int n  = blockIdx.z;
    int t  = threadIdx.x;
    int wave = t >> 6, lane = t & 63;
    int m = lane & 15, quad = lane >> 4;
    int l0 = qb * 128 + wave * 32;

    const unsigned short* qp = Qb + ((size_t)n * LEN + l0 + m) * CH + h * HD + quad * 8;
    short8 bQ[2][2];
    bQ[0][0] = *(const short8*)qp;
    bQ[0][1] = *(const short8*)(qp + 32);
    bQ[1][0] = *(const short8*)(qp + 16 * CH);
    bQ[1][1] = *(const short8*)(qp + 16 * CH + 32);

    float4e Oa[2][4] = {};
    float l_run[2] = {0.0f, 0.0f};
    unsigned short* Pw = Ps + wave * 32 * 136;

    const unsigned short* KgBase = Kb + (size_t)n * LPOOL * CH + h * HD;
    const unsigned short* VgBase = Vb + ((size_t)n * CH + h * HD) * LPOOL;
    const float NEG = -17.312340f;   // -12 * log2(e)

    for (int kt = 0; kt < 8; kt++) {
        __syncthreads();
        {
            const unsigned short* Kg = KgBase + (size_t)kt * 128 * CH;
            #pragma unroll
            for (int i = 0; i < 4; i++) {
                int idx = t + i * 256;
                int row = idx >> 3, ch = idx & 7;
                *(uint4*)&Ks[row * 72 + ch * 8] = *(const uint4*)(Kg + (size_t)row * CH + ch * 8);
            }
        }
        {
            const unsigned short* Vg = VgBase + kt * 128;
            #pragma unroll
            for (int i = 0; i < 4; i++) {
                int idx = t + i * 256;
                int e = idx >> 4, ch = idx & 15;
                *(uint4*)&Vs[e * 136 + ch * 8] = *(const uint4*)(Vg + (size_t)e * LPOOL + ch * 8);
            }
        }
        __syncthreads();

        // scores + exp + pack, per 16-key sub-tile
        #pragma unroll
        for (int kb = 0; kb < 8; kb++) {
            const unsigned short* kp = &Ks[(kb * 16 + m) * 72 + quad * 8];
            short8 a0 = *(const short8*)kp;
            short8 a1 = *(const short8*)(kp + 32);
            #pragma unroll
            for (int qf = 0; qf < 2; qf++) {
                float4e c = {NEG, NEG, NEG, NEG};
                c = __builtin_amdgcn_mfma_f32_16x16x32_bf16(a0, bQ[qf][0], c, 0, 0, 0);
                c = __builtin_amdgcn_mfma_f32_16x16x32_bf16(a1, bQ[qf][1], c, 0, 0, 0);
                float p0 = exp2f(c[0]);
                float p1 = exp2f(c[1]);
                float p2 = exp2f(c[2]);
                float p3 = exp2f(c[3]);
                l_run[qf] += (p0 + p1) + (p2 + p3);
                uint2 pk;
                pk.x = pack2bf(p0, p1);
                pk.y = pack2bf(p2, p3);
                *(uint2*)&Pw[(qf * 16 + m) * 136 + kb * 16 + quad * 4] = pk;
            }
        }

        // PV: O^T += V^T · P^T (per-wave LDS, wave-coherent after lgkmcnt)
        #pragma unroll
        for (int ch2 = 0; ch2 < 4; ch2++) {
            short8 bP0 = *(const short8*)&Pw[m * 136 + ch2 * 32 + quad * 8];
            short8 bP1 = *(const short8*)&Pw[(16 + m) * 136 + ch2 * 32 + quad * 8];
            #pragma unroll
            for (int eb = 0; eb < 4; eb++) {
                short8 aV = *(const short8*)&Vs[(eb * 16 + m) * 136 + ch2 * 32 + quad * 8];
                Oa[0][eb] = __builtin_amdgcn_mfma_f32_16x16x32_bf16(aV, bP0, Oa[0][eb], 0, 0, 0);
                Oa[1][eb] = __builtin_amdgcn_mfma_f32_16x16x32_bf16(aV, bP1, Oa[1][eb], 0, 0, 0);
            }
        }
    }

    // normalize and write O^T bf16 [N, L, C]
    #pragma unroll
    for (int qf = 0; qf < 2; qf++) {
        float l = l_run[qf];
        l += __shfl_xor(l, 16);
        l += __shfl_xor(l, 32);
        float inv = 1.0f / l;
        unsigned short* op = Obf + ((size_t)n * LEN + l0 + qf * 16 + m) * CH + h * HD;
        #pragma unroll
        for (int eb = 0; eb < 4; eb++) {
            uint2 pk;
            pk.x = pack2bf(Oa[qf][eb][0] * inv, Oa[qf][eb][1] * inv);
            pk.y = pack2bf(Oa[qf][eb][2] * inv, Oa[qf][eb][3] * inv);
            *(uint2*)(op + eb * 16 + quad * 4) = pk;
        }
    }
}

// ---------------------------------------------------------------------------
extern "C" void kernel_launch(void* const* d_in, const int* in_sizes, int n_in,
                              void* d_out, int out_size, void* d_ws, size_t ws_size,
                              hipStream_t stream)
{
    const float* x  = (const float*)d_in[0];
    const float* Wq = (const float*)d_in[1];
    const float* bq = (const float*)d_in[2];
    const float* Wk = (const float*)d_in[3];
    const float* bk = (const float*)d_in[4];
    const float* Wv = (const float*)d_in[5];
    const float* bv = (const float*)d_in[6];
    const float* Wo = (const float*)d_in[7];
    const float* bo = (const float*)d_in[8];
    const float* Wa = (const float*)d_in[9];
    const float* g1 = (const float*)d_in[10];
    const float* b1 = (const float*)d_in[11];
    const float* m1 = (const float*)d_in[12];
    const float* v1 = (const float*)d_in[13];
    const float* g2 = (const float*)d_in[14];
    const float* b2 = (const float*)d_in[15];
    const float* m2 = (const float*)d_in[16];
    const float* v2 = (const float*)d_in[17];

    float* wsf      = (float*)d_ws;
    float* bn_scale = wsf;
    float* bn_shift = wsf + 256;
    unsigned short* Wbf   = (unsigned short*)(wsf + 512);           // 5*65536
    unsigned short* xbf   = Wbf + 5 * 65536;                        // [N,L,C]
    unsigned short* poolT = xbf   + (size_t)NBATCH * LEN * CH;      // [N,L2,C]
    unsigned short* xabf  = poolT + (size_t)NBATCH * LPOOL * CH;    // [N,L2,C]
    unsigned short* Kbf   = xabf  + (size_t)NBATCH * LPOOL * CH;    // [N,L2,C]
    unsigned short* Vbf   = Kbf   + (size_t)NBATCH * LPOOL * CH;    // [N,C,L2]
    unsigned short* Qbf   = Vbf   + (size_t)NBATCH * LPOOL * CH;    // [N,L,C]
    unsigned short* Obf   = Qbf   + (size_t)NBATCH * LEN * CH;      // [N,L,C]

    prep_bn<<<1, 256, 0, stream>>>(g1, b1, m1, v1, g2, b2, m2, v2, bn_scale, bn_shift);
    cast_weights<<<320, 256, 0, stream>>>(Wq, Wk, Wv, Wo, Wa, Wbf);
    transpose_cast<<<dim3(64, 4, 4), 256, 0, stream>>>(x, xbf);
    pool_transpose<<<dim3(16, 4, 4), 256, 0, stream>>>(x, poolT);

    // q = Wq @ x + bq, pre-scaled by log2(e)/8 -> Qbf [N,L,C]
    gemm_mfma<<<dim3(32, 2, 4), 256, 0, stream>>>(
        Wbf + 0 * 65536, 0, xbf, (size_t)LEN * CH, bq, nullptr, nullptr, nullptr,
        nullptr, Qbf, LEN, 256, 256, 0.18033688f);

    // xa = BN2(BN1(Wa @ pool(x))) -> xabf [N,L2,C]
    gemm_mfma<<<dim3(8, 2, 4), 256, 0, stream>>>(
        Wbf + 4 * 65536, 0, poolT, (size_t)LPOOL * CH, nullptr, nullptr, bn_scale, bn_shift,
        nullptr, xabf, LPOOL, 256, 256, 1.0f);

    // k = Wk @ xa + bk -> Kbf [N,L2,C]
    gemm_mfma<<<dim3(8, 2, 4), 256, 0, stream>>>(
        Wbf + 1 * 65536, 0, xabf, (size_t)LPOOL * CH, bk, nullptr, nullptr, nullptr,
        nullptr, Kbf, LPOOL, 256, 256, 1.0f);

    // v = Wv @ xa + bv -> Vbf [N,C,L2]  (swapped operands)
    gemm_mfma<<<dim3(2, 8, 4), 256, 0, stream>>>(
        xabf, (size_t)LPOOL * CH, Wbf + 2 * 65536, 0, nullptr, bv, nullptr, nullptr,
        nullptr, Vbf, 256, LPOOL, LPOOL, 1.0f);

    // attention -> Obf [N,L,C] bf16
    attn_mfma<<<dim3(LEN / 128, NH, NBATCH), 256, 0, stream>>>(Qbf, Kbf, Vbf, Obf);

    // out = Wo @ o + bo -> f32 d_out [N,C,L]
    gemm_mfma<<<dim3(32, 2, 4), 256, 0, stream>>>(
        Wbf + 3 * 65536, 0, Obf, (size_t)LEN * CH, bo, nullptr, nullptr, nullptr,
        (float*)d_out, nullptr, LEN, 256, 256, 1.0f);
}

// Round 6
// 180.444 us; speedup vs baseline: 3.1118x; 1.0654x over previous
//
#include <hip/hip_runtime.h>
#include <stdint.h>

// Problem constants
constexpr int NBATCH = 4;
constexpr int CH     = 256;   // channels
constexpr int LEN    = 4096;  // sequence length
constexpr int LPOOL  = 1024;  // pooled length (LEN/4)
constexpr int NH     = 4;     // heads
constexpr int HD     = 64;    // head dim

typedef __attribute__((ext_vector_type(8))) short short8;   // 8 bf16 in 4 VGPRs
typedef __attribute__((ext_vector_type(4))) float float4e;  // MFMA C/D

__device__ __forceinline__ unsigned short f2bf(float f) {
    union { unsigned int i; float f; } v; v.f = f;
    unsigned int lsb = (v.i >> 16) & 1u;
    v.i += 0x7fffu + lsb;
    return (unsigned short)(v.i >> 16);
}
// pack two floats -> two bf16 (round-half-up via +0x8000, then byte-perm)
__device__ __forceinline__ unsigned pack2bf(float lo, float hi) {
    unsigned a = __float_as_uint(lo) + 0x8000u;
    unsigned b = __float_as_uint(hi) + 0x8000u;
    return __builtin_amdgcn_perm(b, a, 0x07060302u);
}

// ---------------------------------------------------------------------------
// Setup: blocks 0..319 cast the 5 weight matrices to bf16; block 320 computes
// the composed BN affine and the concatenated bkv bias.
__global__ __launch_bounds__(256) void setup_kernel(
    const float* __restrict__ w0, const float* __restrict__ w1,
    const float* __restrict__ w2, const float* __restrict__ w3,
    const float* __restrict__ w4, unsigned short* __restrict__ outW,
    const float* __restrict__ g1, const float* __restrict__ b1,
    const float* __restrict__ m1, const float* __restrict__ v1,
    const float* __restrict__ g2, const float* __restrict__ b2,
    const float* __restrict__ m2, const float* __restrict__ v2,
    float* __restrict__ scale, float* __restrict__ shift,
    const float* __restrict__ bk, const float* __restrict__ bv,
    float* __restrict__ bkv)
{
    int b = blockIdx.x, t = threadIdx.x;
    if (b < 320) {
        int gid = b * 256 + t;
        int w = gid >> 14;
        int off = (gid & 16383) * 4;
        const float* src = (w == 0) ? w0 : (w == 1) ? w1 : (w == 2) ? w2 : (w == 3) ? w3 : w4;
        float4 v = *(const float4*)(src + off);
        uint2 pk;
        pk.x = pack2bf(v.x, v.y);
        pk.y = pack2bf(v.z, v.w);
        *(uint2*)(outW + w * 65536 + off) = pk;
    } else {
        float inv1 = g1[t] * rsqrtf(v1[t] + 1e-5f);
        float inv2 = g2[t] * rsqrtf(v2[t] + 1e-5f);
        scale[t] = inv1 * inv2;
        shift[t] = (b1[t] - m1[t] * inv1) * inv2 + (b2[t] - m2[t] * inv2);
        bkv[t] = bk[t];
        bkv[256 + t] = bv[t];
    }
}

// ---------------------------------------------------------------------------
// One pass over x [N,C,L] f32:
//   xbf   [N,L,C]  bf16 (transpose)
//   poolT [N,L2,C] bf16 (mean+max over 4, transposed)
// Block covers 64 c x 64 l  (=> 16 pooled positions).
__global__ __launch_bounds__(256) void transpool(
    const float* __restrict__ x, unsigned short* __restrict__ xbf,
    unsigned short* __restrict__ poolT)
{
    __shared__ float T[64][65];
    __shared__ float P16[64][17];
    int n = blockIdx.z, c0 = blockIdx.y * 64, l0 = blockIdx.x * 64;
    const float* xp = x + ((size_t)n * CH + c0) * LEN + l0;
    int t = threadIdx.x;
    #pragma unroll
    for (int i = 0; i < 4; i++) {
        int idx = t + i * 256;
        int c = idx >> 4, l4 = idx & 15;
        float4 v = *(const float4*)(xp + (size_t)c * LEN + l4 * 4);
        T[c][l4 * 4 + 0] = v.x; T[c][l4 * 4 + 1] = v.y;
        T[c][l4 * 4 + 2] = v.z; T[c][l4 * 4 + 3] = v.w;
        P16[c][l4] = (v.x + v.y + v.z + v.w) * 0.25f
                   + fmaxf(fmaxf(v.x, v.y), fmaxf(v.z, v.w));
    }
    __syncthreads();
    unsigned short* op = xbf + ((size_t)n * LEN + l0) * CH + c0;
    #pragma unroll
    for (int i = 0; i < 4; i++) {
        int idx = t + i * 256;
        int l = idx >> 4, c4 = idx & 15;
        uint2 pk;
        pk.x = pack2bf(T[c4 * 4 + 0][l], T[c4 * 4 + 1][l]);
        pk.y = pack2bf(T[c4 * 4 + 2][l], T[c4 * 4 + 3][l]);
        *(uint2*)(op + (size_t)l * CH + c4 * 4) = pk;
    }
    // pooled: 16 p x 64 c -> poolT[(n*LPOOL + l0/4 + p)*CH + c0 + c]
    int p0 = l0 >> 2;
    #pragma unroll
    for (int k = 0; k < 2; k++) {
        int p = (t >> 5) + k * 8;
        int c2 = (t & 31) * 2;
        unsigned pk = pack2bf(P16[c2][p], P16[c2 + 1][p]);
        *(unsigned*)(poolT + ((size_t)n * LPOOL + p0 + p) * CH + c0 + c2) = pk;
    }
}

// ---------------------------------------------------------------------------
// MFMA GEMM: D[i][j] = sum_k A[i][k] * B[j][k], K = 256 (bf16, K-contig rows).
// Epilogue: + biasRow[i]; *scale[i]+shift[i]; *outScale.
// Output modes (per 128-row tile):
//   outF != 0                : f32 [row][col] (ld NN), LDS-restaged 512B stores
//   rowTile <  rowSplit      : bf16 at out1 + col*cs1 + row  (column-major-ish)
//   rowTile >= rowSplit      : bf16 at out2 + (row-rowSplit)*rs2 + col
__global__ __launch_bounds__(256) void gemm_mfma(
    const unsigned short* __restrict__ A,
    const unsigned short* __restrict__ B, size_t bBatch,
    const float* __restrict__ biasRow,
    const float* __restrict__ scale, const float* __restrict__ shift,
    float* __restrict__ outF, size_t oFBatch,
    unsigned short* __restrict__ out1, size_t o1Batch, int cs1,
    unsigned short* __restrict__ out2, size_t o2Batch, int rs2, int rowSplit,
    int NN, float outScale)
{
    __shared__ unsigned short smem[2 * 128 * 72];  // As | Bs ; reused for epilogue
    unsigned short* As = smem;
    unsigned short* Bs = smem + 128 * 72;

    int n = blockIdx.z;
    int t = threadIdx.x;
    int wave = t >> 6, lane = t & 63, m = lane & 15, quad = lane >> 4;
    int wm = wave & 1, wn = wave >> 1;
    int rowTile = blockIdx.y * 128;
    int col0 = blockIdx.x * 128;

    const unsigned short* Ab = A + (size_t)rowTile * 256;
    const unsigned short* Bb = B + (size_t)n * bBatch + (size_t)col0 * 256;

    float4e acc[4][4] = {};

    for (int kk = 0; kk < 256; kk += 64) {
        #pragma unroll
        for (int i = 0; i < 4; i++) {
            int idx = t + i * 256;
            int row = idx >> 3, ch = idx & 7;
            *(uint4*)&As[row * 72 + ch * 8] = *(const uint4*)(Ab + (size_t)row * 256 + kk + ch * 8);
            *(uint4*)&Bs[row * 72 + ch * 8] = *(const uint4*)(Bb + (size_t)row * 256 + kk + ch * 8);
        }
        __syncthreads();
        #pragma unroll
        for (int kc = 0; kc < 2; kc++) {
            short8 af[4], bfr[4];
            #pragma unroll
            for (int i = 0; i < 4; i++)
                af[i] = *(const short8*)&As[(wm * 64 + i * 16 + m) * 72 + kc * 32 + quad * 8];
            #pragma unroll
            for (int j = 0; j < 4; j++)
                bfr[j] = *(const short8*)&Bs[(wn * 64 + j * 16 + m) * 72 + kc * 32 + quad * 8];
            #pragma unroll
            for (int i = 0; i < 4; i++)
                #pragma unroll
                for (int j = 0; j < 4; j++)
                    acc[i][j] = __builtin_amdgcn_mfma_f32_16x16x32_bf16(af[i], bfr[j], acc[i][j], 0, 0, 0);
        }
        __syncthreads();
    }

    if (outF) {
        // fp32 output, restaged through LDS in two 64-row halves
        float* TOf = (float*)smem;   // [64][128]
        float* dst = outF + (size_t)n * oFBatch;
        #pragma unroll
        for (int half = 0; half < 2; half++) {
            __syncthreads();
            if (wm == half) {
                #pragma unroll
                for (int i = 0; i < 4; i++) {
                    int rowL = i * 16 + quad * 4;
                    int rowG = rowTile + half * 64 + rowL;
                    float br[4], sc[4], sh[4];
                    #pragma unroll
                    for (int r = 0; r < 4; r++) {
                        br[r] = biasRow ? biasRow[rowG + r] : 0.0f;
                        sc[r] = scale ? scale[rowG + r] : 1.0f;
                        sh[r] = shift ? shift[rowG + r] : 0.0f;
                    }
                    #pragma unroll
                    for (int j = 0; j < 4; j++) {
                        int colL = wn * 64 + j * 16 + m;
                        float4e c = acc[i][j];
                        #pragma unroll
                        for (int r = 0; r < 4; r++)
                            TOf[(rowL + r) * 128 + colL] = ((c[r] + br[r]) * sc[r] + sh[r]) * outScale;
                    }
                }
            }
            __syncthreads();
            #pragma unroll
            for (int w = 0; w < 8; w++) {
                int idx = t + w * 256;
                int row = idx >> 5, c4 = idx & 31;
                *(float4*)(dst + (size_t)(rowTile + half * 64 + row) * NN + col0 + c4 * 4) =
                    *(const float4*)&TOf[row * 128 + c4 * 4];
            }
        }
        return;
    }

    bool mode2 = (rowTile >= rowSplit);
    unsigned short* TO = smem;   // [128][136] (mode2) or [col][136]+row (mode1)
    #pragma unroll
    for (int i = 0; i < 4; i++) {
        int rowL = wm * 64 + i * 16 + quad * 4;
        int rowG = rowTile + rowL;
        float br[4], sc[4], sh[4];
        #pragma unroll
        for (int r = 0; r < 4; r++) {
            br[r] = biasRow ? biasRow[rowG + r] : 0.0f;
            sc[r] = scale ? scale[rowG + r] : 1.0f;
            sh[r] = shift ? shift[rowG + r] : 0.0f;
        }
        #pragma unroll
        for (int j = 0; j < 4; j++) {
            int colL = wn * 64 + j * 16 + m;
            float4e c = acc[i][j];
            float v0 = ((c[0] + br[0]) * sc[0] + sh[0]) * outScale;
            float v1 = ((c[1] + br[1]) * sc[1] + sh[1]) * outScale;
            float v2 = ((c[2] + br[2]) * sc[2] + sh[2]) * outScale;
            float v3 = ((c[3] + br[3]) * sc[3] + sh[3]) * outScale;
            if (!mode2) {
                uint2 pk;
                pk.x = pack2bf(v0, v1);
                pk.y = pack2bf(v2, v3);
                *(uint2*)&TO[colL * 136 + rowL] = pk;
            } else {
                TO[(rowL + 0) * 136 + colL] = f2bf(v0);
                TO[(rowL + 1) * 136 + colL] = f2bf(v1);
                TO[(rowL + 2) * 136 + colL] = f2bf(v2);
                TO[(rowL + 3) * 136 + colL] = f2bf(v3);
            }
        }
    }
    __syncthreads();
    if (!mode2) {
        unsigned short* dst = out1 + (size_t)n * o1Batch;
        #pragma unroll
        for (int w = 0; w < 8; w++) {
            int idx = t + w * 256;
            int l = idx >> 4, ch = idx & 15;
            *(uint4*)(dst + (size_t)(col0 + l) * cs1 + rowTile + ch * 8) =
                *(const uint4*)&TO[l * 136 + ch * 8];
        }
    } else {
        unsigned short* dst = out2 + (size_t)n * o2Batch;
        int rowBase = rowTile - rowSplit;
        #pragma unroll
        for (int w = 0; w < 8; w++) {
            int idx = t + w * 256;
            int row = idx >> 4, ch = idx & 15;
            *(uint4*)(dst + (size_t)(rowBase + row) * rs2 + col0 + ch * 8) =
                *(const uint4*)&TO[row * 136 + ch * 8];
        }
    }
}

// ---------------------------------------------------------------------------
// MFMA flash attention, fixed-shift softmax (no online max).
// Qb: [N, L, C] bf16, pre-scaled by log2(e)/8 ; Kb: [N, L2, C] bf16 ;
// Vb: [N, C, L2] bf16 ; Obf: [N, L, C] bf16 (O^T layout, feeds o-proj).
__global__ __launch_bounds__(256) void attn_mfma(
    const unsigned short* __restrict__ Qb,
    const unsigned short* __restrict__ Kb,
    const unsigned short* __restrict__ Vb,
    unsigned short* __restrict__ Obf)
{
    __shared__ unsigned short Ks[128 * 72];      // K-tile [key][e]
    __shared__ unsigned short Vs[64 * 136];      // V^T-tile [e][key]
    __shared__ unsigned short Ps[4 * 32 * 136];  // per-wave P [q][key]

    int qb = blockIdx.x;
    int h  = blockIdx.y;
    int n  = blockIdx.z;
    int t  = threadIdx.x;
    int wave = t >> 6, lane = t & 63;
    int m = lane & 15, quad = lane >> 4;
    int l0 = qb * 128 + wave * 32;

    const unsigned short* qp = Qb + ((size_t)n * LEN + l0 + m) * CH + h * HD + quad * 8;
    short8 bQ[2][2];
    bQ[0][0] = *(const short8*)qp;
    bQ[0][1] = *(const short8*)(qp + 32);
    bQ[1][0] = *(const short8*)(qp + 16 * CH);
    bQ[1][1] = *(const short8*)(qp + 16 * CH + 32);

    float4e Oa[2][4] = {};
    float l_run[2] = {0.0f, 0.0f};
    unsigned short* Pw = Ps + wave * 32 * 136;

    const unsigned short* KgBase = Kb + (size_t)n * LPOOL * CH + h * HD;
    const unsigned short* VgBase = Vb + ((size_t)n * CH + h * HD) * LPOOL;
    const float NEG = -17.312340f;   // -12 * log2(e)

    for (int kt = 0; kt < 8; kt++) {
        __syncthreads();
        {
            const unsigned short* Kg = KgBase + (size_t)kt * 128 * CH;
            #pragma unroll
            for (int i = 0; i < 4; i++) {
                int idx = t + i * 256;
                int row = idx >> 3, ch = idx & 7;
                *(uint4*)&Ks[row * 72 + ch * 8] = *(const uint4*)(Kg + (size_t)row * CH + ch * 8);
            }
        }
        {
            const unsigned short* Vg = VgBase + kt * 128;
            #pragma unroll
            for (int i = 0; i < 4; i++) {
                int idx = t + i * 256;
                int e = idx >> 4, ch = idx & 15;
                *(uint4*)&Vs[e * 136 + ch * 8] = *(const uint4*)(Vg + (size_t)e * LPOOL + ch * 8);
            }
        }
        __syncthreads();

        #pragma unroll
        for (int kb = 0; kb < 8; kb++) {
            const unsigned short* kp = &Ks[(kb * 16 + m) * 72 + quad * 8];
            short8 a0 = *(const short8*)kp;
            short8 a1 = *(const short8*)(kp + 32);
            #pragma unroll
            for (int qf = 0; qf < 2; qf++) {
                float4e c = {NEG, NEG, NEG, NEG};
                c = __builtin_amdgcn_mfma_f32_16x16x32_bf16(a0, bQ[qf][0], c, 0, 0, 0);
                c = __builtin_amdgcn_mfma_f32_16x16x32_bf16(a1, bQ[qf][1], c, 0, 0, 0);
                float p0 = exp2f(c[0]);
                float p1 = exp2f(c[1]);
                float p2 = exp2f(c[2]);
                float p3 = exp2f(c[3]);
                l_run[qf] += (p0 + p1) + (p2 + p3);
                uint2 pk;
                pk.x = pack2bf(p0, p1);
                pk.y = pack2bf(p2, p3);
                *(uint2*)&Pw[(qf * 16 + m) * 136 + kb * 16 + quad * 4] = pk;
            }
        }

        #pragma unroll
        for (int ch2 = 0; ch2 < 4; ch2++) {
            short8 bP0 = *(const short8*)&Pw[m * 136 + ch2 * 32 + quad * 8];
            short8 bP1 = *(const short8*)&Pw[(16 + m) * 136 + ch2 * 32 + quad * 8];
            #pragma unroll
            for (int eb = 0; eb < 4; eb++) {
                short8 aV = *(const short8*)&Vs[(eb * 16 + m) * 136 + ch2 * 32 + quad * 8];
                Oa[0][eb] = __builtin_amdgcn_mfma_f32_16x16x32_bf16(aV, bP0, Oa[0][eb], 0, 0, 0);
                Oa[1][eb] = __builtin_amdgcn_mfma_f32_16x16x32_bf16(aV, bP1, Oa[1][eb], 0, 0, 0);
            }
        }
    }

    #pragma unroll
    for (int qf = 0; qf < 2; qf++) {
        float l = l_run[qf];
        l += __shfl_xor(l, 16);
        l += __shfl_xor(l, 32);
        float inv = 1.0f / l;
        unsigned short* op = Obf + ((size_t)n * LEN + l0 + qf * 16 + m) * CH + h * HD;
        #pragma unroll
        for (int eb = 0; eb < 4; eb++) {
            uint2 pk;
            pk.x = pack2bf(Oa[qf][eb][0] * inv, Oa[qf][eb][1] * inv);
            pk.y = pack2bf(Oa[qf][eb][2] * inv, Oa[qf][eb][3] * inv);
            *(uint2*)(op + eb * 16 + quad * 4) = pk;
        }
    }
}

// ---------------------------------------------------------------------------
extern "C" void kernel_launch(void* const* d_in, const int* in_sizes, int n_in,
                              void* d_out, int out_size, void* d_ws, size_t ws_size,
                              hipStream_t stream)
{
    const float* x  = (const float*)d_in[0];
    const float* Wq = (const float*)d_in[1];
    const float* bq = (const float*)d_in[2];
    const float* Wk = (const float*)d_in[3];
    const float* bk = (const float*)d_in[4];
    const float* Wv = (const float*)d_in[5];
    const float* bv = (const float*)d_in[6];
    const float* Wo = (const float*)d_in[7];
    const float* bo = (const float*)d_in[8];
    const float* Wa = (const float*)d_in[9];
    const float* g1 = (const float*)d_in[10];
    const float* b1 = (const float*)d_in[11];
    const float* m1 = (const float*)d_in[12];
    const float* v1 = (const float*)d_in[13];
    const float* g2 = (const float*)d_in[14];
    const float* b2 = (const float*)d_in[15];
    const float* m2 = (const float*)d_in[16];
    const float* v2 = (const float*)d_in[17];

    float* wsf      = (float*)d_ws;
    float* bn_scale = wsf;            // 256
    float* bn_shift = wsf + 256;      // 256
    float* bkv      = wsf + 512;      // 512
    unsigned short* Wbf   = (unsigned short*)(wsf + 1024);          // 5*65536
    unsigned short* xbf   = Wbf + 5 * 65536;                        // [N,L,C]
    unsigned short* poolT = xbf   + (size_t)NBATCH * LEN * CH;      // [N,L2,C]
    unsigned short* xabf  = poolT + (size_t)NBATCH * LPOOL * CH;    // [N,L2,C]
    unsigned short* Kbf   = xabf  + (size_t)NBATCH * LPOOL * CH;    // [N,L2,C]
    unsigned short* Vbf   = Kbf   + (size_t)NBATCH * LPOOL * CH;    // [N,C,L2]
    unsigned short* Qbf   = Vbf   + (size_t)NBATCH * LPOOL * CH;    // [N,L,C]
    unsigned short* Obf   = Qbf   + (size_t)NBATCH * LEN * CH;      // [N,L,C]

    // 1. setup: weights->bf16, BN affine, bkv concat
    setup_kernel<<<321, 256, 0, stream>>>(Wq, Wk, Wv, Wo, Wa, Wbf,
        g1, b1, m1, v1, g2, b2, m2, v2, bn_scale, bn_shift, bk, bv, bkv);

    // 2. transpose + pool in one pass over x
    transpool<<<dim3(64, 4, 4), 256, 0, stream>>>(x, xbf, poolT);

    // 3. q = Wq @ x + bq, pre-scaled by log2(e)/8 -> Qbf [N,L,C]
    gemm_mfma<<<dim3(32, 2, 4), 256, 0, stream>>>(
        Wbf + 0 * 65536, xbf, (size_t)LEN * CH, bq, nullptr, nullptr,
        nullptr, 0, Qbf, (size_t)LEN * CH, 256, nullptr, 0, 0, 1 << 30,
        LEN, 0.18033688f);

    // 4. xa = BN2(BN1(Wa @ pool(x))) -> xabf [N,L2,C]
    gemm_mfma<<<dim3(8, 2, 4), 256, 0, stream>>>(
        Wbf + 4 * 65536, poolT, (size_t)LPOOL * CH, nullptr, bn_scale, bn_shift,
        nullptr, 0, xabf, (size_t)LPOOL * CH, 256, nullptr, 0, 0, 1 << 30,
        LPOOL, 1.0f);

    // 5. fused k+v: A = [Wk;Wv] (contiguous in Wbf), M=512.
    //    rows 0..255 -> Kbf [l2][c] (mode1); rows 256..511 -> Vbf [c][l2] (mode2)
    gemm_mfma<<<dim3(8, 4, 4), 256, 0, stream>>>(
        Wbf + 1 * 65536, xabf, (size_t)LPOOL * CH, bkv, nullptr, nullptr,
        nullptr, 0, Kbf, (size_t)LPOOL * CH, 256, Vbf, (size_t)LPOOL * CH, LPOOL, 256,
        LPOOL, 1.0f);

    // 6. attention -> Obf [N,L,C] bf16
    attn_mfma<<<dim3(LEN / 128, NH, NBATCH), 256, 0, stream>>>(Qbf, Kbf, Vbf, Obf);

    // 7. out = Wo @ o + bo -> f32 d_out [N,C,L]
    gemm_mfma<<<dim3(32, 2, 4), 256, 0, stream>>>(
        Wbf + 3 * 65536, Obf, (size_t)LEN * CH, bo, nullptr, nullptr,
        (float*)d_out, (size_t)CH * LEN, nullptr, 0, 0, nullptr, 0, 0, 1 << 30,
        LEN, 1.0f);
}